// Round 14
// baseline (118.496 us; speedup 1.0000x reference)
//
#include <hip/hip_runtime.h>
#include <math.h>

typedef float        f32x2 __attribute__((ext_vector_type(2)));
typedef float        f32x4 __attribute__((ext_vector_type(4)));
typedef _Float16     f16x2 __attribute__((ext_vector_type(2)));
typedef _Float16     f16x8 __attribute__((ext_vector_type(8)));
typedef unsigned int u32;
typedef unsigned int u32x2 __attribute__((ext_vector_type(2)));
typedef unsigned int u32x4 __attribute__((ext_vector_type(4)));

// Problem constants
#define HW_    4096
#define CH_STR 8192          // channel (or o) stride in x/out = D*HW
#define B_STR  262144        // batch stride = C*D*HW
#define NPIX   131072
#define NKSTEP 18            // 576 rlen4-padded k-slots / 32
#define NSLICE 72            // 576 / 8
#define NCT2   76            // slices padded (+1 step) for 2-deep prefetch
#define NBEL   (NKSTEP*4*64*8)     // 36864 frag elems (73,728 B)

// Scales: u' = 1024*u, w' = 512*w  ->  acc = 2^19*oc; atan2 scale-invariant.
#define WSCALE 512.0f
#define USCALE 1024.0f

// d_ws: frag _Float16[36864] at +0 (73,728 B); ct2 u32[2*76] at +73728 (608 B).

// ---------------------------------------------------------------------------
// Prep. k-enumeration = rows c padded to rlen4(c)=4*(c/4+1) slots (total 576;
// kpbase4(c)=4*(c+2a(a-1)+ab), a=c>>2,b=c&3 — formula validated R2-R6).
// frag[ks][var*2+oh][lane][j]: fp16 RNE split of 512*foldW at
// k = ks*32+8*(lane>>4)+j, o = oh*16+(lane&15); fold e<c: W[o,c,e]+W[o,e,c],
// e==c: W[o,c,c], pad(e>c): 0.
// ct2[2s+h] (h=seg) = (c*8)<<16 | e0*8  (byte offsets) for k = 8s+4h;
// every 4-aligned run lies in one row (rows are 4-multiples). Zero-padded.
// ---------------------------------------------------------------------------
__global__ void prep(const float* __restrict__ w,
                     _Float16* __restrict__ bfr,
                     u32* __restrict__ ct2) {
    int idx = blockIdx.x * 256 + threadIdx.x;
    if (idx < NBEL) {
        int j    =  idx & 7;
        int lane = (idx >> 3) & 63;
        int frag = (idx >> 9) & 3;      // var*2 + oh
        int ks   =  idx >> 11;
        int var  = frag >> 1;
        int oh   = frag & 1;
        int k = ks * 32 + ((lane >> 4) << 3) + j;
        int c = 0, base = 0;
        for (; c < 32; ++c) { int rl = ((c >> 2) + 1) << 2; if (k < base + rl) break; base += rl; }
        int e = k - base;
        int o = oh * 16 + (lane & 15);
        float v = 0.0f;
        if (e <= c)
            v = (e == c) ? w[o * 1024 + c * 33]
                         : (w[o * 1024 + c * 32 + e] + w[o * 1024 + e * 32 + c]);
        v *= WSCALE;
        _Float16 h = (_Float16)v;                    // RNE hi
        if (var) h = (_Float16)(v - (float)h);       // RNE residual (lo)
        bfr[idx] = h;
    } else if (idx < NBEL + 2 * NCT2) {
        int t = idx - NBEL;
        int s = t >> 1, half = t & 1;
        u32 v = 0;
        if (s < NSLICE) {
            int k = s * 8 + half * 4, c = 0, base = 0;
            for (; c < 32; ++c) { int rl = ((c >> 2) + 1) << 2; if (k < base + rl) break; base += rl; }
            v = ((u32)(c * 8) << 16) | (u32)((k - base) * 8);
        }
        ct2[t] = v;
    }
}

// ---------------------------------------------------------------------------
// Main (MFMA structure/indices validated R8-R12). Block = 256 thr = 4 waves,
// each wave owns 16 px; wave tile 16px x 32o; K = 576 in 18 steps of 32.
// Each lane's 8 A-elements = two 4-segments (seg h: row c_h, e in
// [e0_h, e0_h+4)). acc = Ah*Bh + Ah*Bl + Al*Bh in fp32 MFMA accs.
// Trig: interleaved UNSCALED (cos,sin) pairs only, [px][67 dwords] =
// 17,152 B LDS -> 8 blocks/CU resident (grid 2048 = exactly one cohort,
// 8 waves/SIMD). c-side scale applied in-register.
// ---------------------------------------------------------------------------
#define TPB   256
#define TSTR  67    // trig row stride (dwords); 67 mod 32 = 3 spreads banks

__device__ __forceinline__ f16x8 pack8(u32 a, u32 b, u32 c, u32 d) {
    u32x4 t = {a, b, c, d};
    return __builtin_bit_cast(f16x8, t);
}
__device__ __forceinline__ u32 pkrtz_u(float a, float b) {
    return __builtin_bit_cast(u32, __builtin_amdgcn_cvt_pkrtz(a, b));
}

__global__ __launch_bounds__(TPB, 8) void mfma_bilinear(
    const float* __restrict__ x,
    const _Float16* __restrict__ bfr,
    const u32* __restrict__ ct2,
    const float* __restrict__ bias,
    float* __restrict__ out)
{
    __shared__ float trig[64 * TSTR];   // 17,152 B

    const int lane = threadIdx.x & 63;
    const int wv   = threadIdx.x >> 6;       // wave id 0..3
    const int lg   = lane >> 4;              // k-subgroup 0..3
    const int lidm = lane & 15;              // A-row / B-col within fragment
    const int P0   = blockIdx.x * 64;
    const int b    = P0 >> 13;
    const int d    = (P0 >> 12) & 1;
    const int hw0  = P0 & 4095;              // 64-aligned, block stays in (b,d)
    const int obase = b * B_STR + d * HW_ + hw0;   // + px + (c|o)*CH_STR

    const int px = wv * 16 + lidm;           // block-local pixel (my A-row)
    float* tp = trig + px * TSTR;
    const char* tb = (const char*)tp;        // byte base of my trig row

    // ---- trig prologue: 4 lanes (lg=0..3) cover the 32 channels of px ----
    #pragma unroll
    for (int m = 0; m < 8; ++m) {
        int c = lg * 8 + m;
        float xv = x[obase + px + c * CH_STR];
        float s, co; __sincosf(xv, &s, &co);
        *(f32x2*)(tb + 8 * c) = (f32x2){co, s};
    }
    // same-wave DS ordering makes the reads below safe without a barrier.

    f32x4 acc_r[2] = {{0.f,0.f,0.f,0.f}, {0.f,0.f,0.f,0.f}};
    f32x4 acc_i[2] = {{0.f,0.f,0.f,0.f}, {0.f,0.f,0.f,0.f}};

    // Streaming pointers: uniform base + lane voffset + imm offsets.
    const char* ubp = (const char*)bfr;      // step-ks B block (+= 4096)
    const char* uct = (const char*)ct2;      // step-ks ct2 row (+= 32)
    const int lo16 = lane * 16;
    const int lg8  = lg * 8;

#define LDB(OFF)   (*(const f16x8*)(ubp + lo16 + (OFF)))
#define LDCT(OFF)  (*(const u32x2*)(uct + lg8 + (OFF)))
#define LOAD_TRIG(ST, CS0, P00, P01, CS1, P10, P11) do { \
    const u32x2 st_ = (ST); \
    const int cB0 = (int)(st_.x >> 16), eB0 = (int)(st_.x & 0xffffu); \
    const int cB1 = (int)(st_.y >> 16), eB1 = (int)(st_.y & 0xffffu); \
    CS0 = *(const f32x2*)(tb + cB0); \
    P00 = *(const f32x4*)(tb + eB0); \
    P01 = *(const f32x4*)(tb + eB0 + 16); \
    CS1 = *(const f32x2*)(tb + cB1); \
    P10 = *(const f32x4*)(tb + eB1); \
    P11 = *(const f32x4*)(tb + eB1 + 16); \
} while (0)

// One k-step: u-gen (2 segments) + fp16 RTZ 2-split + 12 MFMA.
#define COMPUTE_STEP(CS0, P00, P01, CS1, P10, P11, BH0, BH1, BL0, BL1) do { \
    const float cc0 = (CS0)[0] * USCALE, sc0 = (CS0)[1] * USCALE; \
    const float cc1 = (CS1)[0] * USCALE, sc1 = (CS1)[1] * USCALE; \
    u32 hr[4], hi[4], lr[4], li[4]; \
    _Pragma("unroll") \
    for (int p = 0; p < 4; ++p) { \
        const f32x4 pe = (p == 0) ? (P00) : (p == 1) ? (P01) : (p == 2) ? (P10) : (P11); \
        const float ccs = (p < 2) ? cc0 : cc1; \
        const float scs = (p < 2) ? sc0 : sc1; \
        const float cea = pe[0], sea = pe[1], ceb = pe[2], seb = pe[3]; \
        const float ur0 = fmaf(ccs, cea, -(scs * sea)); \
        const float ui0 = fmaf(ccs, sea,   scs * cea); \
        const float ur1 = fmaf(ccs, ceb, -(scs * seb)); \
        const float ui1 = fmaf(ccs, seb,   scs * ceb); \
        hr[p] = pkrtz_u(ur0, ur1); \
        hi[p] = pkrtz_u(ui0, ui1); \
        const f16x2 h2r = __builtin_bit_cast(f16x2, hr[p]); \
        const f16x2 h2i = __builtin_bit_cast(f16x2, hi[p]); \
        lr[p] = pkrtz_u(ur0 - (float)h2r[0], ur1 - (float)h2r[1]); \
        li[p] = pkrtz_u(ui0 - (float)h2i[0], ui1 - (float)h2i[1]); \
    } \
    const f16x8 ahr = pack8(hr[0], hr[1], hr[2], hr[3]); \
    const f16x8 ahi = pack8(hi[0], hi[1], hi[2], hi[3]); \
    const f16x8 alr = pack8(lr[0], lr[1], lr[2], lr[3]); \
    const f16x8 ali = pack8(li[0], li[1], li[2], li[3]); \
    acc_r[0] = __builtin_amdgcn_mfma_f32_16x16x32_f16(ahr, BH0, acc_r[0], 0, 0, 0); \
    acc_i[0] = __builtin_amdgcn_mfma_f32_16x16x32_f16(ahi, BH0, acc_i[0], 0, 0, 0); \
    acc_r[1] = __builtin_amdgcn_mfma_f32_16x16x32_f16(ahr, BH1, acc_r[1], 0, 0, 0); \
    acc_i[1] = __builtin_amdgcn_mfma_f32_16x16x32_f16(ahi, BH1, acc_i[1], 0, 0, 0); \
    acc_r[0] = __builtin_amdgcn_mfma_f32_16x16x32_f16(ahr, BL0, acc_r[0], 0, 0, 0); \
    acc_i[0] = __builtin_amdgcn_mfma_f32_16x16x32_f16(ahi, BL0, acc_i[0], 0, 0, 0); \
    acc_r[1] = __builtin_amdgcn_mfma_f32_16x16x32_f16(ahr, BL1, acc_r[1], 0, 0, 0); \
    acc_i[1] = __builtin_amdgcn_mfma_f32_16x16x32_f16(ahi, BL1, acc_i[1], 0, 0, 0); \
    acc_r[0] = __builtin_amdgcn_mfma_f32_16x16x32_f16(alr, BH0, acc_r[0], 0, 0, 0); \
    acc_i[0] = __builtin_amdgcn_mfma_f32_16x16x32_f16(ali, BH0, acc_i[0], 0, 0, 0); \
    acc_r[1] = __builtin_amdgcn_mfma_f32_16x16x32_f16(alr, BH1, acc_r[1], 0, 0, 0); \
    acc_i[1] = __builtin_amdgcn_mfma_f32_16x16x32_f16(ali, BH1, acc_i[1], 0, 0, 0); \
} while (0)

    // ---- pipeline prologue: step-0 state + ct2 words for step 1 ----
    f16x8 bh0 = LDB(0), bh1 = LDB(1024), bl0 = LDB(2048), bl1 = LDB(3072);
    f32x2 cs0, cs1; f32x4 p00, p01, p10, p11;
    LOAD_TRIG(LDCT(0), cs0, p00, p01, cs1, p10, p11);
    u32x2 stN = LDCT(32);
    ubp += 4096;                         // -> step 1 block

    #pragma unroll 2
    for (int ks = 0; ks < NKSTEP - 1; ++ks) {
        f16x8 nbh0 = LDB(0), nbh1 = LDB(1024), nbl0 = LDB(2048), nbl1 = LDB(3072);
        f32x2 ncs0, ncs1; f32x4 np00, np01, np10, np11;
        LOAD_TRIG(stN, ncs0, np00, np01, ncs1, np10, np11);
        u32x2 stN2 = LDCT(64);           // words(ks+2); padded table keeps in-bounds

        COMPUTE_STEP(cs0, p00, p01, cs1, p10, p11, bh0, bh1, bl0, bl1);

        bh0 = nbh0; bh1 = nbh1; bl0 = nbl0; bl1 = nbl1;
        cs0 = ncs0; cs1 = ncs1;
        p00 = np00; p01 = np01; p10 = np10; p11 = np11;
        stN = stN2;
        ubp += 4096; uct += 32;
    }
    COMPUTE_STEP(cs0, p00, p01, cs1, p10, p11, bh0, bh1, bl0, bl1);  // peeled last

    // ---- epilogue: C/D (m89): col o = oh*16 + (lane&15), row px = 4*lg + q ----
    #pragma unroll
    for (int oh = 0; oh < 2; ++oh) {
        const int o = oh * 16 + lidm;
        const float bo = bias[o];
        #pragma unroll
        for (int q = 0; q < 4; ++q) {
            const int pxr = wv * 16 + lg * 4 + q;
            out[obase + pxr + o * CH_STR] = atan2f(acc_i[oh][q], acc_r[oh][q]) + bo;
        }
    }
#undef LDB
#undef LDCT
#undef LOAD_TRIG
#undef COMPUTE_STEP
}

// ---------------------------------------------------------------------------
extern "C" void kernel_launch(void* const* d_in, const int* in_sizes, int n_in,
                              void* d_out, int out_size, void* d_ws, size_t ws_size,
                              hipStream_t stream) {
    const float* x    = (const float*)d_in[0];
    const float* w    = (const float*)d_in[1];
    const float* bias = (const float*)d_in[2];
    float* out        = (float*)d_out;
    _Float16* bfr = (_Float16*)d_ws;                  // 73,728 B
    u32*      ct2 = (u32*)((char*)d_ws + 73728);      // 608 B

    {
        int n = NBEL + 2 * NCT2;
        prep<<<(n + 255) / 256, 256, 0, stream>>>(w, bfr, ct2);
    }
    {
        int grid = NPIX / 64;   // 2048 blocks = 8 blocks/CU x 256 CU, one cohort
        mfma_bilinear<<<grid, TPB, 0, stream>>>(x, bfr, ct2, bias, out);
    }
}

// Round 15
// 115.183 us; speedup vs baseline: 1.0288x; 1.0288x over previous
//
#include <hip/hip_runtime.h>
#include <math.h>

typedef float        f32x2 __attribute__((ext_vector_type(2)));
typedef float        f32x4 __attribute__((ext_vector_type(4)));
typedef _Float16     f16x2 __attribute__((ext_vector_type(2)));
typedef _Float16     f16x8 __attribute__((ext_vector_type(8)));
typedef unsigned int u32;
typedef unsigned int u32x2 __attribute__((ext_vector_type(2)));
typedef unsigned int u32x4 __attribute__((ext_vector_type(4)));

// Problem constants
#define HW_    4096
#define CH_STR 8192          // channel (or o) stride in x/out = D*HW
#define B_STR  262144        // batch stride = C*D*HW
#define NPIX   131072
#define NKSTEP 18            // 576 rlen4-padded k-slots / 32
#define NSLICE 72            // 576 / 8
#define NCT2   76            // slices padded (+1 step) for 2-deep prefetch
#define NBEL   (NKSTEP*4*64*8)     // 36864 frag elems (73,728 B)

// Scales: u' = 1024*u, w' = 512*w  ->  acc = 2^19*oc; atan2 scale-invariant.
#define WSCALE 512.0f
#define USCALE 1024.0f

// d_ws: frag _Float16[36864] at +0 (73,728 B); ct2 u32[2*76] at +73728 (608 B).

// ---------------------------------------------------------------------------
// Prep (validated R13: absmax 0.015625). k-enumeration = rows c padded to
// rlen4(c)=4*(c/4+1) slots (total 576). frag[ks][var*2+oh][lane][j]: fp16 RNE
// split of 512*foldW at k = ks*32+8*(lane>>4)+j, o = oh*16+(lane&15);
// fold e<c: W[o,c,e]+W[o,e,c], e==c: W[o,c,c], pad: 0.
// ct2[2s+h] = (c*8)<<16 | e0*8 (byte offsets) for k = 8s+4h; zero-padded.
// ---------------------------------------------------------------------------
__global__ void prep(const float* __restrict__ w,
                     _Float16* __restrict__ bfr,
                     u32* __restrict__ ct2) {
    int idx = blockIdx.x * 256 + threadIdx.x;
    if (idx < NBEL) {
        int j    =  idx & 7;
        int lane = (idx >> 3) & 63;
        int frag = (idx >> 9) & 3;      // var*2 + oh
        int ks   =  idx >> 11;
        int var  = frag >> 1;
        int oh   = frag & 1;
        int k = ks * 32 + ((lane >> 4) << 3) + j;
        int c = 0, base = 0;
        for (; c < 32; ++c) { int rl = ((c >> 2) + 1) << 2; if (k < base + rl) break; base += rl; }
        int e = k - base;
        int o = oh * 16 + (lane & 15);
        float v = 0.0f;
        if (e <= c)
            v = (e == c) ? w[o * 1024 + c * 33]
                         : (w[o * 1024 + c * 32 + e] + w[o * 1024 + e * 32 + c]);
        v *= WSCALE;
        _Float16 h = (_Float16)v;                    // RNE hi
        if (var) h = (_Float16)(v - (float)h);       // RNE residual (lo)
        bfr[idx] = h;
    } else if (idx < NBEL + 2 * NCT2) {
        int t = idx - NBEL;
        int s = t >> 1, half = t & 1;
        u32 v = 0;
        if (s < NSLICE) {
            int k = s * 8 + half * 4, c = 0, base = 0;
            for (; c < 32; ++c) { int rl = ((c >> 2) + 1) << 2; if (k < base + rl) break; base += rl; }
            v = ((u32)(c * 8) << 16) | (u32)((k - base) * 8);
        }
        ct2[t] = v;
    }
}

// ---------------------------------------------------------------------------
// Main (MFMA structure/indices validated R8-R13). Block = 256 thr = 4 waves,
// each wave owns 16 px; wave tile 16px x 32o; K = 576 in 18 steps of 32.
// acc = Ah*Bh + Ah*Bl + Al*Bh in fp32 MFMA accs.
// Trig: interleaved UNSCALED (cos,sin) pairs, [px][67 dwords] = 17,152 B LDS
// -> 9 blocks/CU by LDS; with VGPR<=64 the HW reaches the 32-waves/CU cap
// (8 waves/SIMD) WITHOUT launch_bounds forcing.
// R14 vs R13: __launch_bounds__(256,4) — R13's (256,8) forced VGPR to 32 and
// spilled the pipeline to scratch (WRITE_SIZE 16->47 MB, dur 49->119 us).
// ---------------------------------------------------------------------------
#define TPB   256
#define TSTR  67    // trig row stride (dwords); 67 mod 32 = 3 spreads banks

__device__ __forceinline__ f16x8 pack8(u32 a, u32 b, u32 c, u32 d) {
    u32x4 t = {a, b, c, d};
    return __builtin_bit_cast(f16x8, t);
}
__device__ __forceinline__ u32 pkrtz_u(float a, float b) {
    return __builtin_bit_cast(u32, __builtin_amdgcn_cvt_pkrtz(a, b));
}

__global__ __launch_bounds__(TPB, 4) void mfma_bilinear(
    const float* __restrict__ x,
    const _Float16* __restrict__ bfr,
    const u32* __restrict__ ct2,
    const float* __restrict__ bias,
    float* __restrict__ out)
{
    __shared__ float trig[64 * TSTR];   // 17,152 B

    const int lane = threadIdx.x & 63;
    const int wv   = threadIdx.x >> 6;       // wave id 0..3
    const int lg   = lane >> 4;              // k-subgroup 0..3
    const int lidm = lane & 15;              // A-row / B-col within fragment
    const int P0   = blockIdx.x * 64;
    const int b    = P0 >> 13;
    const int d    = (P0 >> 12) & 1;
    const int hw0  = P0 & 4095;              // 64-aligned, block stays in (b,d)
    const int obase = b * B_STR + d * HW_ + hw0;   // + px + (c|o)*CH_STR

    const int px = wv * 16 + lidm;           // block-local pixel (my A-row)
    float* tp = trig + px * TSTR;
    const char* tb = (const char*)tp;        // byte base of my trig row

    // ---- trig prologue: 4 lanes (lg=0..3) cover the 32 channels of px ----
    #pragma unroll
    for (int m = 0; m < 8; ++m) {
        int c = lg * 8 + m;
        float xv = x[obase + px + c * CH_STR];
        float s, co; __sincosf(xv, &s, &co);
        *(f32x2*)(tb + 8 * c) = (f32x2){co, s};
    }
    // same-wave DS ordering makes the reads below safe without a barrier.

    f32x4 acc_r[2] = {{0.f,0.f,0.f,0.f}, {0.f,0.f,0.f,0.f}};
    f32x4 acc_i[2] = {{0.f,0.f,0.f,0.f}, {0.f,0.f,0.f,0.f}};

    // Streaming pointers: uniform base + lane voffset + imm offsets.
    const char* ubp = (const char*)bfr;      // step-ks B block (+= 4096)
    const char* uct = (const char*)ct2;      // step-ks ct2 row (+= 32)
    const int lo16 = lane * 16;
    const int lg8  = lg * 8;

#define LDB(OFF)   (*(const f16x8*)(ubp + lo16 + (OFF)))
#define LDCT(OFF)  (*(const u32x2*)(uct + lg8 + (OFF)))
#define LOAD_TRIG(ST, CS0, P00, P01, CS1, P10, P11) do { \
    const u32x2 st_ = (ST); \
    const int cB0 = (int)(st_.x >> 16), eB0 = (int)(st_.x & 0xffffu); \
    const int cB1 = (int)(st_.y >> 16), eB1 = (int)(st_.y & 0xffffu); \
    CS0 = *(const f32x2*)(tb + cB0); \
    P00 = *(const f32x4*)(tb + eB0); \
    P01 = *(const f32x4*)(tb + eB0 + 16); \
    CS1 = *(const f32x2*)(tb + cB1); \
    P10 = *(const f32x4*)(tb + eB1); \
    P11 = *(const f32x4*)(tb + eB1 + 16); \
} while (0)

// One k-step: u-gen (2 segments) + fp16 RTZ 2-split + 12 MFMA.
#define COMPUTE_STEP(CS0, P00, P01, CS1, P10, P11, BH0, BH1, BL0, BL1) do { \
    const float cc0 = (CS0)[0] * USCALE, sc0 = (CS0)[1] * USCALE; \
    const float cc1 = (CS1)[0] * USCALE, sc1 = (CS1)[1] * USCALE; \
    u32 hr[4], hi[4], lr[4], li[4]; \
    _Pragma("unroll") \
    for (int p = 0; p < 4; ++p) { \
        const f32x4 pe = (p == 0) ? (P00) : (p == 1) ? (P01) : (p == 2) ? (P10) : (P11); \
        const float ccs = (p < 2) ? cc0 : cc1; \
        const float scs = (p < 2) ? sc0 : sc1; \
        const float cea = pe[0], sea = pe[1], ceb = pe[2], seb = pe[3]; \
        const float ur0 = fmaf(ccs, cea, -(scs * sea)); \
        const float ui0 = fmaf(ccs, sea,   scs * cea); \
        const float ur1 = fmaf(ccs, ceb, -(scs * seb)); \
        const float ui1 = fmaf(ccs, seb,   scs * ceb); \
        hr[p] = pkrtz_u(ur0, ur1); \
        hi[p] = pkrtz_u(ui0, ui1); \
        const f16x2 h2r = __builtin_bit_cast(f16x2, hr[p]); \
        const f16x2 h2i = __builtin_bit_cast(f16x2, hi[p]); \
        lr[p] = pkrtz_u(ur0 - (float)h2r[0], ur1 - (float)h2r[1]); \
        li[p] = pkrtz_u(ui0 - (float)h2i[0], ui1 - (float)h2i[1]); \
    } \
    const f16x8 ahr = pack8(hr[0], hr[1], hr[2], hr[3]); \
    const f16x8 ahi = pack8(hi[0], hi[1], hi[2], hi[3]); \
    const f16x8 alr = pack8(lr[0], lr[1], lr[2], lr[3]); \
    const f16x8 ali = pack8(li[0], li[1], li[2], li[3]); \
    acc_r[0] = __builtin_amdgcn_mfma_f32_16x16x32_f16(ahr, BH0, acc_r[0], 0, 0, 0); \
    acc_i[0] = __builtin_amdgcn_mfma_f32_16x16x32_f16(ahi, BH0, acc_i[0], 0, 0, 0); \
    acc_r[1] = __builtin_amdgcn_mfma_f32_16x16x32_f16(ahr, BH1, acc_r[1], 0, 0, 0); \
    acc_i[1] = __builtin_amdgcn_mfma_f32_16x16x32_f16(ahi, BH1, acc_i[1], 0, 0, 0); \
    acc_r[0] = __builtin_amdgcn_mfma_f32_16x16x32_f16(ahr, BL0, acc_r[0], 0, 0, 0); \
    acc_i[0] = __builtin_amdgcn_mfma_f32_16x16x32_f16(ahi, BL0, acc_i[0], 0, 0, 0); \
    acc_r[1] = __builtin_amdgcn_mfma_f32_16x16x32_f16(ahr, BL1, acc_r[1], 0, 0, 0); \
    acc_i[1] = __builtin_amdgcn_mfma_f32_16x16x32_f16(ahi, BL1, acc_i[1], 0, 0, 0); \
    acc_r[0] = __builtin_amdgcn_mfma_f32_16x16x32_f16(alr, BH0, acc_r[0], 0, 0, 0); \
    acc_i[0] = __builtin_amdgcn_mfma_f32_16x16x32_f16(ali, BH0, acc_i[0], 0, 0, 0); \
    acc_r[1] = __builtin_amdgcn_mfma_f32_16x16x32_f16(alr, BH1, acc_r[1], 0, 0, 0); \
    acc_i[1] = __builtin_amdgcn_mfma_f32_16x16x32_f16(ali, BH1, acc_i[1], 0, 0, 0); \
} while (0)

    // ---- pipeline prologue: step-0 state + ct2 words for step 1 ----
    f16x8 bh0 = LDB(0), bh1 = LDB(1024), bl0 = LDB(2048), bl1 = LDB(3072);
    f32x2 cs0, cs1; f32x4 p00, p01, p10, p11;
    LOAD_TRIG(LDCT(0), cs0, p00, p01, cs1, p10, p11);
    u32x2 stN = LDCT(32);
    ubp += 4096;                         // -> step 1 block

    #pragma unroll 2
    for (int ks = 0; ks < NKSTEP - 1; ++ks) {
        f16x8 nbh0 = LDB(0), nbh1 = LDB(1024), nbl0 = LDB(2048), nbl1 = LDB(3072);
        f32x2 ncs0, ncs1; f32x4 np00, np01, np10, np11;
        LOAD_TRIG(stN, ncs0, np00, np01, ncs1, np10, np11);
        u32x2 stN2 = LDCT(64);           // words(ks+2); padded table keeps in-bounds

        COMPUTE_STEP(cs0, p00, p01, cs1, p10, p11, bh0, bh1, bl0, bl1);

        bh0 = nbh0; bh1 = nbh1; bl0 = nbl0; bl1 = nbl1;
        cs0 = ncs0; cs1 = ncs1;
        p00 = np00; p01 = np01; p10 = np10; p11 = np11;
        stN = stN2;
        ubp += 4096; uct += 32;
    }
    COMPUTE_STEP(cs0, p00, p01, cs1, p10, p11, bh0, bh1, bl0, bl1);  // peeled last

    // ---- epilogue: C/D (m89): col o = oh*16 + (lane&15), row px = 4*lg + q ----
    #pragma unroll
    for (int oh = 0; oh < 2; ++oh) {
        const int o = oh * 16 + lidm;
        const float bo = bias[o];
        #pragma unroll
        for (int q = 0; q < 4; ++q) {
            const int pxr = wv * 16 + lg * 4 + q;
            out[obase + pxr + o * CH_STR] = atan2f(acc_i[oh][q], acc_r[oh][q]) + bo;
        }
    }
#undef LDB
#undef LDCT
#undef LOAD_TRIG
#undef COMPUTE_STEP
}

// ---------------------------------------------------------------------------
extern "C" void kernel_launch(void* const* d_in, const int* in_sizes, int n_in,
                              void* d_out, int out_size, void* d_ws, size_t ws_size,
                              hipStream_t stream) {
    const float* x    = (const float*)d_in[0];
    const float* w    = (const float*)d_in[1];
    const float* bias = (const float*)d_in[2];
    float* out        = (float*)d_out;
    _Float16* bfr = (_Float16*)d_ws;                  // 73,728 B
    u32*      ct2 = (u32*)((char*)d_ws + 73728);      // 608 B

    {
        int n = NBEL + 2 * NCT2;
        prep<<<(n + 255) / 256, 256, 0, stream>>>(w, bfr, ct2);
    }
    {
        int grid = NPIX / 64;   // 2048 blocks x 4 waves
        mfma_bilinear<<<grid, TPB, 0, stream>>>(x, bfr, ct2, bias, out);
    }
}

// Round 16
// 53.230 us; speedup vs baseline: 2.2261x; 2.1639x over previous
//
#include <hip/hip_runtime.h>
#include <math.h>

typedef float        f32x2 __attribute__((ext_vector_type(2)));
typedef float        f32x4 __attribute__((ext_vector_type(4)));
typedef _Float16     f16x2 __attribute__((ext_vector_type(2)));
typedef _Float16     f16x8 __attribute__((ext_vector_type(8)));
typedef unsigned int u32;
typedef unsigned int u32x4 __attribute__((ext_vector_type(4)));

// Problem constants
#define HW_    4096
#define CH_STR 8192          // channel (or o) stride in x/out = D*HW
#define B_STR  262144        // batch stride = C*D*HW
#define NPIX   131072
#define NKSTEP 20            // 640 padded k-slots / 32
#define NSLICE 80            // 640 / 8
#define NCT    84            // ct padded (+1 step) so 2-deep prefetch stays in bounds
#define NBEL   (NKSTEP*2*2*64*8)   // 40960 frag elems

// Scales: u' = 1024*u, w' = 512*w  ->  acc = 2^19 * oc; atan2 is scale-invariant.
#define WSCALE 512.0f
#define USCALE 1024.0f

// d_ws layout: frag _Float16[40960] at +0 (81,920 B); ct u32[84] at +81920.

// ---------------------------------------------------------------------------
// Prep (R12's, validated): frag[ks][var*2+oh][lane][j] = fp16 RNE split of
// 512*foldW at k = ks*32+8*(lane>>4)+j (rows c padded to rlen8(c)=8*(c/8+1),
// total 640), o = oh*16+(lane&15). fold e<c: W[o,c,e]+W[o,e,c]; e==c:
// W[o,c,c]; pad: 0.  ct[s] = (c*4)<<16 | e0*4  (dword->byte offsets for the
// R15 trig layout: cos at +cB, sin at +128+cB). Zero-padded to 84.
// ---------------------------------------------------------------------------
__global__ void prep(const float* __restrict__ w,
                     _Float16* __restrict__ bfr,
                     u32* __restrict__ ct) {
    int idx = blockIdx.x * 256 + threadIdx.x;
    if (idx < NBEL) {
        int j    =  idx & 7;
        int lane = (idx >> 3) & 63;
        int frag = (idx >> 9) & 3;      // var*2 + oh
        int ks   =  idx >> 11;
        int var  = frag >> 1;
        int oh   = frag & 1;
        int k = ks * 32 + ((lane >> 4) << 3) + j;
        int c = 0, base = 0;
        for (; c < 32; ++c) { int rl = 8 * ((c >> 3) + 1); if (k < base + rl) break; base += rl; }
        int e = k - base;
        int o = oh * 16 + (lane & 15);
        float v = 0.0f;
        if (e <= c)
            v = (e == c) ? w[o * 1024 + c * 33]
                         : (w[o * 1024 + c * 32 + e] + w[o * 1024 + e * 32 + c]);
        v *= WSCALE;
        _Float16 h = (_Float16)v;                    // RNE hi
        if (var) h = (_Float16)(v - (float)h);       // RNE residual (lo)
        bfr[idx] = h;
    } else if (idx < NBEL + NCT) {
        int s = idx - NBEL;
        u32 v = 0;
        if (s < NSLICE) {
            int k = s * 8, c = 0, base = 0;
            for (; c < 32; ++c) { int rl = 8 * ((c >> 3) + 1); if (k < base + rl) break; base += rl; }
            v = ((u32)(c * 4) << 16) | (u32)((k - base) * 4);
        }
        ct[s] = v;
    }
}

// ---------------------------------------------------------------------------
// Main. R15 = R12 (49.0 us codegen, VGPR 52 / SGPR 112) with ONE change:
// trig LDS halved to unscaled cos[32]+sin[32] per px, stride 68 dwords
// (272 B, 16B-aligned) -> 17,408 B/block -> 9 blocks/CU by LDS (R12's
// 33.8 KB capped 4). USCALE applied via 2 register mults per k-step.
// Everything else byte-identical to R12: K=640 in 20 steps, streaming
// uniform B pointer + imm offsets, single ct word, unroll 4, peeled tail.
// acc = Ah*Bh + Ah*Bl + Al*Bh in fp32 MFMA accumulators.
// ---------------------------------------------------------------------------
#define TPB   256
#define TSTR  68    // trig row stride (dwords) = 272 B, multiple of 16

__device__ __forceinline__ f16x8 pack8(u32 a, u32 b, u32 c, u32 d) {
    u32x4 t = {a, b, c, d};
    return __builtin_bit_cast(f16x8, t);
}
__device__ __forceinline__ u32 pkrtz_u(float a, float b) {
    return __builtin_bit_cast(u32, __builtin_amdgcn_cvt_pkrtz(a, b));
}

__global__ __launch_bounds__(TPB, 4) void mfma_bilinear(
    const float* __restrict__ x,
    const _Float16* __restrict__ bfr,
    const u32* __restrict__ ct,
    const float* __restrict__ bias,
    float* __restrict__ out)
{
    __shared__ float trig[64 * TSTR];   // 17,408 B

    const int lane = threadIdx.x & 63;
    const int wv   = threadIdx.x >> 6;       // wave id 0..3
    const int lg   = lane >> 4;              // k-subgroup 0..3
    const int lidm = lane & 15;              // A-row / B-col within fragment
    const int P0   = blockIdx.x * 64;
    const int b    = P0 >> 13;
    const int d    = (P0 >> 12) & 1;
    const int hw0  = P0 & 4095;              // 64-aligned, block stays in (b,d)
    const int obase = b * B_STR + d * HW_ + hw0;   // + px + (c|o)*CH_STR

    const int px = wv * 16 + lidm;           // block-local pixel (my A-row)
    float* tp = trig + px * TSTR;
    const char* tb = (const char*)tp;        // byte base of my trig row

    // ---- trig prologue: 4 lanes (lg=0..3) cover the 32 channels of px ----
    #pragma unroll
    for (int m = 0; m < 8; ++m) {
        int c = lg * 8 + m;
        float xv = x[obase + px + c * CH_STR];
        float s, co; __sincosf(xv, &s, &co);
        tp[c]      = co;
        tp[32 + c] = s;
    }
    // same-wave DS ordering makes the reads below safe without a barrier.

    f32x4 acc_r[2] = {{0.f,0.f,0.f,0.f}, {0.f,0.f,0.f,0.f}};
    f32x4 acc_i[2] = {{0.f,0.f,0.f,0.f}, {0.f,0.f,0.f,0.f}};

    // Streaming pointers: uniform base + (lane/lg) voffset + imm offsets.
    const char* ubp = (const char*)bfr;      // step-ks B block at ubp (+= 4096)
    const char* uct = (const char*)ct;       // word(ks) at uct (+= 16)
    const int lo16 = lane * 16;
    const int lg4  = lg * 4;

#define LDB(OFF)      (*(const f16x8*)(ubp + lo16 + (OFF)))
#define LDCT(OFF)     (*(const u32*)(uct + lg4 + (OFF)))
#define LOAD_TRIG(ST, CC, SC, CE0, CE1, SE0, SE1) do { \
    const u32 st_ = (ST); \
    const int cB = (int)(st_ >> 16), eB = (int)(st_ & 0xffffu); \
    CC  = *(const float*)(tb + cB); \
    SC  = *(const float*)(tb + 128 + cB); \
    CE0 = *(const f32x4*)(tb + eB); \
    CE1 = *(const f32x4*)(tb + eB + 16); \
    SE0 = *(const f32x4*)(tb + 128 + eB); \
    SE1 = *(const f32x4*)(tb + 144 + eB); \
} while (0)

// One k-step: u-gen + fp16 RTZ 2-split + 12 MFMA (validated structure).
#define COMPUTE_STEP(CC, SC, CE0, CE1, SE0, SE1, BH0, BH1, BL0, BL1) do { \
    const float ccs = (CC) * USCALE; \
    const float scs = (SC) * USCALE; \
    u32 hr[4], hi[4], lr[4], li[4]; \
    _Pragma("unroll") \
    for (int p = 0; p < 4; ++p) { \
        const float cea = (2*p     < 4) ? (CE0)[2*p]     : (CE1)[2*p - 4]; \
        const float sea = (2*p     < 4) ? (SE0)[2*p]     : (SE1)[2*p - 4]; \
        const float ceb = (2*p + 1 < 4) ? (CE0)[2*p + 1] : (CE1)[2*p - 3]; \
        const float seb = (2*p + 1 < 4) ? (SE0)[2*p + 1] : (SE1)[2*p - 3]; \
        const float ur0 = fmaf(ccs, cea, -(scs * sea)); \
        const float ui0 = fmaf(ccs, sea,   scs * cea); \
        const float ur1 = fmaf(ccs, ceb, -(scs * seb)); \
        const float ui1 = fmaf(ccs, seb,   scs * ceb); \
        hr[p] = pkrtz_u(ur0, ur1); \
        hi[p] = pkrtz_u(ui0, ui1); \
        const f16x2 h2r = __builtin_bit_cast(f16x2, hr[p]); \
        const f16x2 h2i = __builtin_bit_cast(f16x2, hi[p]); \
        lr[p] = pkrtz_u(ur0 - (float)h2r[0], ur1 - (float)h2r[1]); \
        li[p] = pkrtz_u(ui0 - (float)h2i[0], ui1 - (float)h2i[1]); \
    } \
    const f16x8 ahr = pack8(hr[0], hr[1], hr[2], hr[3]); \
    const f16x8 ahi = pack8(hi[0], hi[1], hi[2], hi[3]); \
    const f16x8 alr = pack8(lr[0], lr[1], lr[2], lr[3]); \
    const f16x8 ali = pack8(li[0], li[1], li[2], li[3]); \
    acc_r[0] = __builtin_amdgcn_mfma_f32_16x16x32_f16(ahr, BH0, acc_r[0], 0, 0, 0); \
    acc_i[0] = __builtin_amdgcn_mfma_f32_16x16x32_f16(ahi, BH0, acc_i[0], 0, 0, 0); \
    acc_r[1] = __builtin_amdgcn_mfma_f32_16x16x32_f16(ahr, BH1, acc_r[1], 0, 0, 0); \
    acc_i[1] = __builtin_amdgcn_mfma_f32_16x16x32_f16(ahi, BH1, acc_i[1], 0, 0, 0); \
    acc_r[0] = __builtin_amdgcn_mfma_f32_16x16x32_f16(ahr, BL0, acc_r[0], 0, 0, 0); \
    acc_i[0] = __builtin_amdgcn_mfma_f32_16x16x32_f16(ahi, BL0, acc_i[0], 0, 0, 0); \
    acc_r[1] = __builtin_amdgcn_mfma_f32_16x16x32_f16(ahr, BL1, acc_r[1], 0, 0, 0); \
    acc_i[1] = __builtin_amdgcn_mfma_f32_16x16x32_f16(ahi, BL1, acc_i[1], 0, 0, 0); \
    acc_r[0] = __builtin_amdgcn_mfma_f32_16x16x32_f16(alr, BH0, acc_r[0], 0, 0, 0); \
    acc_i[0] = __builtin_amdgcn_mfma_f32_16x16x32_f16(ali, BH0, acc_i[0], 0, 0, 0); \
    acc_r[1] = __builtin_amdgcn_mfma_f32_16x16x32_f16(alr, BH1, acc_r[1], 0, 0, 0); \
    acc_i[1] = __builtin_amdgcn_mfma_f32_16x16x32_f16(ali, BH1, acc_i[1], 0, 0, 0); \
} while (0)

    // ---- pipeline prologue: step-0 state + slice word for step 1 ----
    f16x8 bh0 = LDB(0), bh1 = LDB(1024), bl0 = LDB(2048), bl1 = LDB(3072);
    float cc, sc; f32x4 ce0, ce1, se0, se1;
    LOAD_TRIG(LDCT(0), cc, sc, ce0, ce1, se0, se1);
    u32 stN = LDCT(16);
    ubp += 4096;                         // -> step 1 block

    #pragma unroll 4
    for (int ks = 0; ks < NKSTEP - 1; ++ks) {
        // prefetch step ks+1 (B block at ubp; trig via stN; word for ks+2)
        f16x8 nbh0 = LDB(0), nbh1 = LDB(1024), nbl0 = LDB(2048), nbl1 = LDB(3072);
        float ncc, nsc; f32x4 nce0, nce1, nse0, nse1;
        LOAD_TRIG(stN, ncc, nsc, nce0, nce1, nse0, nse1);
        u32 stN2 = LDCT(32);             // word(ks+2); padded table keeps it in-bounds

        COMPUTE_STEP(cc, sc, ce0, ce1, se0, se1, bh0, bh1, bl0, bl1);

        bh0 = nbh0; bh1 = nbh1; bl0 = nbl0; bl1 = nbl1;
        cc = ncc; sc = nsc;
        ce0 = nce0; ce1 = nce1; se0 = nse0; se1 = nse1;
        stN = stN2;
        ubp += 4096; uct += 16;
    }
    // peeled final step (no prefetch, no clamps anywhere)
    COMPUTE_STEP(cc, sc, ce0, ce1, se0, se1, bh0, bh1, bl0, bl1);

    // ---- epilogue: C/D (m89): col o = oh*16 + (lane&15), row px = 4*lg + q ----
    #pragma unroll
    for (int oh = 0; oh < 2; ++oh) {
        const int o = oh * 16 + lidm;
        const float bo = bias[o];
        #pragma unroll
        for (int q = 0; q < 4; ++q) {
            const int pxr = wv * 16 + lg * 4 + q;
            out[obase + pxr + o * CH_STR] = atan2f(acc_i[oh][q], acc_r[oh][q]) + bo;
        }
    }
#undef LDB
#undef LDCT
#undef LOAD_TRIG
#undef COMPUTE_STEP
}

// ---------------------------------------------------------------------------
extern "C" void kernel_launch(void* const* d_in, const int* in_sizes, int n_in,
                              void* d_out, int out_size, void* d_ws, size_t ws_size,
                              hipStream_t stream) {
    const float* x    = (const float*)d_in[0];
    const float* w    = (const float*)d_in[1];
    const float* bias = (const float*)d_in[2];
    float* out        = (float*)d_out;
    _Float16* bfr = (_Float16*)d_ws;                  // 81,920 B
    u32*      ct  = (u32*)((char*)d_ws + 81920);      // 336 B

    {
        int n = NBEL + NCT;
        prep<<<(n + 255) / 256, 256, 0, stream>>>(w, bfr, ct);
    }
    {
        int grid = NPIX / 64;   // 2048 blocks x 4 waves
        mfma_bilinear<<<grid, TPB, 0, stream>>>(x, bfr, ct, bias, out);
    }
}

// Round 17
// 51.155 us; speedup vs baseline: 2.3164x; 1.0406x over previous
//
#include <hip/hip_runtime.h>
#include <math.h>

typedef float        f32x4 __attribute__((ext_vector_type(4)));
typedef _Float16     f16x2 __attribute__((ext_vector_type(2)));
typedef _Float16     f16x8 __attribute__((ext_vector_type(8)));
typedef unsigned int u32;
typedef unsigned int u32x4 __attribute__((ext_vector_type(4)));

// Problem constants
#define HW_    4096
#define CH_STR 8192          // channel (or o) stride in x/out = D*HW
#define B_STR  262144        // batch stride = C*D*HW
#define NPIX   131072
#define NKSTEP 18            // 576 rlen4-padded k-slots / 32
#define NSLICE 72            // 576 / 8
#define NCT    76            // +1 step pad for 2-deep descriptor prefetch
#define NBEL   (NKSTEP*2*2*64*8)   // 36864 frag elems (73,728 B)

// Scales: u' = 1024*u, w' = 512*w  ->  acc = 2^19*oc; atan2 scale-invariant.
#define WSCALE 512.0f
#define USCALE 1024.0f

// d_ws: frag _Float16[36864] at +0 (73,728 B); ct u32[76] at +73728 (304 B).

// ---------------------------------------------------------------------------
// Prep (fold + rlen4 search validated R13: passed absmax 0.015625).
// k-enumeration = rows c padded to rlen4(c)=4*(c/4+1) (total 576).
// frag[ks][var*2+oh][lane][j]: fp16 RNE split (var=0 hi, 1 residual) of
// 512*foldW at k = ks*32+8*(lane>>4)+j, o = oh*16+(lane&15);
// fold e<c: W[o,c,e]+W[o,e,c]; e==c: W[o,c,c]; pad: 0.
// ct[s] packs BYTE offsets for slice s's two 4-segments (k=8s and k=8s+4,
// each within one row since rows are x4): (cB0<<24)|(eB0<<16)|(cB1<<8)|eB1,
// cB=c*4, eB=e0*4, all <=124. Zero-padded to 76 words.
// ---------------------------------------------------------------------------
__global__ void prep(const float* __restrict__ w,
                     _Float16* __restrict__ bfr,
                     u32* __restrict__ ct) {
    int idx = blockIdx.x * 256 + threadIdx.x;
    if (idx < NBEL) {
        int j    =  idx & 7;
        int lane = (idx >> 3) & 63;
        int frag = (idx >> 9) & 3;      // var*2 + oh
        int ks   =  idx >> 11;
        int var  = frag >> 1;
        int oh   = frag & 1;
        int k = ks * 32 + ((lane >> 4) << 3) + j;
        int c = 0, base = 0;
        for (; c < 32; ++c) { int rl = ((c >> 2) + 1) << 2; if (k < base + rl) break; base += rl; }
        int e = k - base;
        int o = oh * 16 + (lane & 15);
        float v = 0.0f;
        if (e <= c)
            v = (e == c) ? w[o * 1024 + c * 33]
                         : (w[o * 1024 + c * 32 + e] + w[o * 1024 + e * 32 + c]);
        v *= WSCALE;
        _Float16 h = (_Float16)v;                    // RNE hi
        if (var) h = (_Float16)(v - (float)h);       // RNE residual (lo)
        bfr[idx] = h;
    } else if (idx < NBEL + NCT) {
        int s = idx - NBEL;
        u32 v = 0;
        if (s < NSLICE) {
            int cb[2], eb[2];
            #pragma unroll
            for (int h = 0; h < 2; ++h) {
                int k = s * 8 + h * 4, c = 0, base = 0;
                for (; c < 32; ++c) { int rl = ((c >> 2) + 1) << 2; if (k < base + rl) break; base += rl; }
                cb[h] = c * 4; eb[h] = (k - base) * 4;
            }
            v = ((u32)cb[0] << 24) | ((u32)eb[0] << 16) | ((u32)cb[1] << 8) | (u32)eb[1];
        }
        ct[s] = v;
    }
}

// ---------------------------------------------------------------------------
// Main. R16 = R15's exact structure (best kernel: 47.6 us) with K 640->576:
// -10% MFMA / B-bytes / u-gen VALU. Each 32-k step = four 4-segments; trig
// row layout unchanged (cos[32] + sin[32], stride 68 dwords = 272 B, 16B-
// aligned -> all f32x4 LDS reads aligned; R13/R14's 268 B rows broke this).
// Block = 256 thr = 4 waves, each wave owns 16 px; wave tile 16px x 32o.
// acc = Ah*Bh + Ah*Bl + Al*Bh in fp32 MFMA accumulators.
// ---------------------------------------------------------------------------
#define TPB   256
#define TSTR  68    // trig row stride (dwords) = 272 B, multiple of 16

__device__ __forceinline__ f16x8 pack8(u32 a, u32 b, u32 c, u32 d) {
    u32x4 t = {a, b, c, d};
    return __builtin_bit_cast(f16x8, t);
}
__device__ __forceinline__ u32 pkrtz_u(float a, float b) {
    return __builtin_bit_cast(u32, __builtin_amdgcn_cvt_pkrtz(a, b));
}

__global__ __launch_bounds__(TPB, 4) void mfma_bilinear(
    const float* __restrict__ x,
    const _Float16* __restrict__ bfr,
    const u32* __restrict__ ct,
    const float* __restrict__ bias,
    float* __restrict__ out)
{
    __shared__ float trig[64 * TSTR];   // 17,408 B

    const int lane = threadIdx.x & 63;
    const int wv   = threadIdx.x >> 6;       // wave id 0..3
    const int lg   = lane >> 4;              // k-subgroup 0..3
    const int lidm = lane & 15;              // A-row / B-col within fragment
    const int P0   = blockIdx.x * 64;
    const int b    = P0 >> 13;
    const int d    = (P0 >> 12) & 1;
    const int hw0  = P0 & 4095;              // 64-aligned, block stays in (b,d)
    const int obase = b * B_STR + d * HW_ + hw0;   // + px + (c|o)*CH_STR

    const int px = wv * 16 + lidm;           // block-local pixel (my A-row)
    float* tp = trig + px * TSTR;
    const char* tb = (const char*)tp;        // byte base of my trig row

    // ---- trig prologue: 4 lanes (lg=0..3) cover the 32 channels of px ----
    #pragma unroll
    for (int m = 0; m < 8; ++m) {
        int c = lg * 8 + m;
        float xv = x[obase + px + c * CH_STR];
        float s, co; __sincosf(xv, &s, &co);
        tp[c]      = co;
        tp[32 + c] = s;
    }
    // same-wave DS ordering makes the reads below safe without a barrier.

    f32x4 acc_r[2] = {{0.f,0.f,0.f,0.f}, {0.f,0.f,0.f,0.f}};
    f32x4 acc_i[2] = {{0.f,0.f,0.f,0.f}, {0.f,0.f,0.f,0.f}};

    // Streaming pointers: uniform base + (lane/lg) voffset + imm offsets.
    const char* ubp = (const char*)bfr;      // step-ks B block at ubp (+= 4096)
    const char* uct = (const char*)ct;       // word(ks) at uct (+= 16)
    const int lo16 = lane * 16;
    const int lg4  = lg * 4;

#define LDB(OFF)      (*(const f16x8*)(ubp + lo16 + (OFF)))
#define LDCT(OFF)     (*(const u32*)(uct + lg4 + (OFF)))
// Decode packed byte-offsets; all f32x4 reads 16B-aligned (eB multiple of 16).
#define LOAD_TRIG(ST, CC0, SC0, CE0, SE0, CC1, SC1, CE1, SE1) do { \
    const u32 st_ = (ST); \
    const int cB0 = (int)(st_ >> 24); \
    const int eB0 = (int)((st_ >> 16) & 0xffu); \
    const int cB1 = (int)((st_ >> 8) & 0xffu); \
    const int eB1 = (int)(st_ & 0xffu); \
    CC0 = *(const float*)(tb + cB0); \
    SC0 = *(const float*)(tb + 128 + cB0); \
    CE0 = *(const f32x4*)(tb + eB0); \
    SE0 = *(const f32x4*)(tb + 128 + eB0); \
    CC1 = *(const float*)(tb + cB1); \
    SC1 = *(const float*)(tb + 128 + cB1); \
    CE1 = *(const f32x4*)(tb + eB1); \
    SE1 = *(const f32x4*)(tb + 128 + eB1); \
} while (0)

// One k-step: u-gen (2 segments) + fp16 RTZ 2-split + 12 MFMA.
#define COMPUTE_STEP(CC0, SC0, CE0, SE0, CC1, SC1, CE1, SE1, BH0, BH1, BL0, BL1) do { \
    const float cs0c = (CC0) * USCALE, cs0s = (SC0) * USCALE; \
    const float cs1c = (CC1) * USCALE, cs1s = (SC1) * USCALE; \
    u32 hr[4], hi[4], lr[4], li[4]; \
    _Pragma("unroll") \
    for (int p = 0; p < 4; ++p) { \
        const float ccs = (p < 2) ? cs0c : cs1c; \
        const float scs = (p < 2) ? cs0s : cs1s; \
        const int i0 = (p & 1) * 2; \
        const float cea = (p < 2) ? (CE0)[i0]     : (CE1)[i0]; \
        const float sea = (p < 2) ? (SE0)[i0]     : (SE1)[i0]; \
        const float ceb = (p < 2) ? (CE0)[i0 + 1] : (CE1)[i0 + 1]; \
        const float seb = (p < 2) ? (SE0)[i0 + 1] : (SE1)[i0 + 1]; \
        const float ur0 = fmaf(ccs, cea, -(scs * sea)); \
        const float ui0 = fmaf(ccs, sea,   scs * cea); \
        const float ur1 = fmaf(ccs, ceb, -(scs * seb)); \
        const float ui1 = fmaf(ccs, seb,   scs * ceb); \
        hr[p] = pkrtz_u(ur0, ur1); \
        hi[p] = pkrtz_u(ui0, ui1); \
        const f16x2 h2r = __builtin_bit_cast(f16x2, hr[p]); \
        const f16x2 h2i = __builtin_bit_cast(f16x2, hi[p]); \
        lr[p] = pkrtz_u(ur0 - (float)h2r[0], ur1 - (float)h2r[1]); \
        li[p] = pkrtz_u(ui0 - (float)h2i[0], ui1 - (float)h2i[1]); \
    } \
    const f16x8 ahr = pack8(hr[0], hr[1], hr[2], hr[3]); \
    const f16x8 ahi = pack8(hi[0], hi[1], hi[2], hi[3]); \
    const f16x8 alr = pack8(lr[0], lr[1], lr[2], lr[3]); \
    const f16x8 ali = pack8(li[0], li[1], li[2], li[3]); \
    acc_r[0] = __builtin_amdgcn_mfma_f32_16x16x32_f16(ahr, BH0, acc_r[0], 0, 0, 0); \
    acc_i[0] = __builtin_amdgcn_mfma_f32_16x16x32_f16(ahi, BH0, acc_i[0], 0, 0, 0); \
    acc_r[1] = __builtin_amdgcn_mfma_f32_16x16x32_f16(ahr, BH1, acc_r[1], 0, 0, 0); \
    acc_i[1] = __builtin_amdgcn_mfma_f32_16x16x32_f16(ahi, BH1, acc_i[1], 0, 0, 0); \
    acc_r[0] = __builtin_amdgcn_mfma_f32_16x16x32_f16(ahr, BL0, acc_r[0], 0, 0, 0); \
    acc_i[0] = __builtin_amdgcn_mfma_f32_16x16x32_f16(ahi, BL0, acc_i[0], 0, 0, 0); \
    acc_r[1] = __builtin_amdgcn_mfma_f32_16x16x32_f16(ahr, BL1, acc_r[1], 0, 0, 0); \
    acc_i[1] = __builtin_amdgcn_mfma_f32_16x16x32_f16(ahi, BL1, acc_i[1], 0, 0, 0); \
    acc_r[0] = __builtin_amdgcn_mfma_f32_16x16x32_f16(alr, BH0, acc_r[0], 0, 0, 0); \
    acc_i[0] = __builtin_amdgcn_mfma_f32_16x16x32_f16(ali, BH0, acc_i[0], 0, 0, 0); \
    acc_r[1] = __builtin_amdgcn_mfma_f32_16x16x32_f16(alr, BH1, acc_r[1], 0, 0, 0); \
    acc_i[1] = __builtin_amdgcn_mfma_f32_16x16x32_f16(ali, BH1, acc_i[1], 0, 0, 0); \
} while (0)

    // ---- pipeline prologue: step-0 state + descriptor for step 1 ----
    f16x8 bh0 = LDB(0), bh1 = LDB(1024), bl0 = LDB(2048), bl1 = LDB(3072);
    float cc0, sc0, cc1, sc1; f32x4 ce0, se0, ce1, se1;
    LOAD_TRIG(LDCT(0), cc0, sc0, ce0, se0, cc1, sc1, ce1, se1);
    u32 stN = LDCT(16);
    ubp += 4096;                         // -> step 1 block

    #pragma unroll 4
    for (int ks = 0; ks < NKSTEP - 1; ++ks) {
        // prefetch step ks+1 (B block at ubp; trig via stN; word for ks+2)
        f16x8 nbh0 = LDB(0), nbh1 = LDB(1024), nbl0 = LDB(2048), nbl1 = LDB(3072);
        float ncc0, nsc0, ncc1, nsc1; f32x4 nce0, nse0, nce1, nse1;
        LOAD_TRIG(stN, ncc0, nsc0, nce0, nse0, ncc1, nsc1, nce1, nse1);
        u32 stN2 = LDCT(32);             // word(ks+2); padded table keeps in-bounds

        COMPUTE_STEP(cc0, sc0, ce0, se0, cc1, sc1, ce1, se1, bh0, bh1, bl0, bl1);

        bh0 = nbh0; bh1 = nbh1; bl0 = nbl0; bl1 = nbl1;
        cc0 = ncc0; sc0 = nsc0; cc1 = ncc1; sc1 = nsc1;
        ce0 = nce0; se0 = nse0; ce1 = nce1; se1 = nse1;
        stN = stN2;
        ubp += 4096; uct += 16;
    }
    // peeled final step (no prefetch, no clamps anywhere)
    COMPUTE_STEP(cc0, sc0, ce0, se0, cc1, sc1, ce1, se1, bh0, bh1, bl0, bl1);

    // ---- epilogue: C/D (m89): col o = oh*16 + (lane&15), row px = 4*lg + q ----
    #pragma unroll
    for (int oh = 0; oh < 2; ++oh) {
        const int o = oh * 16 + lidm;
        const float bo = bias[o];
        #pragma unroll
        for (int q = 0; q < 4; ++q) {
            const int pxr = wv * 16 + lg * 4 + q;
            out[obase + pxr + o * CH_STR] = atan2f(acc_i[oh][q], acc_r[oh][q]) + bo;
        }
    }
#undef LDB
#undef LDCT
#undef LOAD_TRIG
#undef COMPUTE_STEP
}

// ---------------------------------------------------------------------------
extern "C" void kernel_launch(void* const* d_in, const int* in_sizes, int n_in,
                              void* d_out, int out_size, void* d_ws, size_t ws_size,
                              hipStream_t stream) {
    const float* x    = (const float*)d_in[0];
    const float* w    = (const float*)d_in[1];
    const float* bias = (const float*)d_in[2];
    float* out        = (float*)d_out;
    _Float16* bfr = (_Float16*)d_ws;                  // 73,728 B
    u32*      ct  = (u32*)((char*)d_ws + 73728);      // 304 B

    {
        int n = NBEL + NCT;
        prep<<<(n + 255) / 256, 256, 0, stream>>>(w, bfr, ct);
    }
    {
        int grid = NPIX / 64;   // 2048 blocks x 4 waves
        mfma_bilinear<<<grid, TPB, 0, stream>>>(x, bfr, ct, bias, out);
    }
}

// Round 18
// 49.764 us; speedup vs baseline: 2.3811x; 1.0279x over previous
//
#include <hip/hip_runtime.h>
#include <math.h>

typedef float        f32x4 __attribute__((ext_vector_type(4)));
typedef _Float16     f16x2 __attribute__((ext_vector_type(2)));
typedef _Float16     f16x8 __attribute__((ext_vector_type(8)));
typedef unsigned int u32;
typedef unsigned int u32x4 __attribute__((ext_vector_type(4)));

// Problem constants
#define HW_    4096
#define CH_STR 8192          // channel (or o) stride in x/out = D*HW
#define B_STR  262144        // batch stride = C*D*HW
#define NPIX   131072
#define NKSTEP 18            // 576 rlen4-padded k-slots / 32
#define NSLICE 72            // 576 / 8
#define NCT    76            // +1 step pad for 2-deep descriptor prefetch
#define NBEL   (NKSTEP*2*2*64*8)   // 36864 frag elems (73,728 B)

// Scales: u' = 1024*u, w' = 512*w  ->  acc = 2^19*oc; atan2 scale-invariant.
#define WSCALE 512.0f
#define USCALE 1024.0f

// d_ws: frag _Float16[36864] at +0 (73,728 B); ct u32[76] at +73728 (304 B).

// ---------------------------------------------------------------------------
// Prep (validated R16: absmax 0.015625). Rows c padded to rlen4(c)=4*(c/4+1)
// (total 576). frag[ks][var*2+oh][lane][j]: fp16 RNE split of 512*foldW at
// k = ks*32+8*(lane>>4)+j, o = oh*16+(lane&15).
// ct[s] = (cB0<<24)|(eB0<<16)|(cB1<<8)|eB1 byte offsets for slice s's two
// 4-segments. Zero-padded to 76 words.
// ---------------------------------------------------------------------------
__global__ void prep(const float* __restrict__ w,
                     _Float16* __restrict__ bfr,
                     u32* __restrict__ ct) {
    int idx = blockIdx.x * 256 + threadIdx.x;
    if (idx < NBEL) {
        int j    =  idx & 7;
        int lane = (idx >> 3) & 63;
        int frag = (idx >> 9) & 3;      // var*2 + oh
        int ks   =  idx >> 11;
        int var  = frag >> 1;
        int oh   = frag & 1;
        int k = ks * 32 + ((lane >> 4) << 3) + j;
        int c = 0, base = 0;
        for (; c < 32; ++c) { int rl = ((c >> 2) + 1) << 2; if (k < base + rl) break; base += rl; }
        int e = k - base;
        int o = oh * 16 + (lane & 15);
        float v = 0.0f;
        if (e <= c)
            v = (e == c) ? w[o * 1024 + c * 33]
                         : (w[o * 1024 + c * 32 + e] + w[o * 1024 + e * 32 + c]);
        v *= WSCALE;
        _Float16 h = (_Float16)v;                    // RNE hi
        if (var) h = (_Float16)(v - (float)h);       // RNE residual (lo)
        bfr[idx] = h;
    } else if (idx < NBEL + NCT) {
        int s = idx - NBEL;
        u32 v = 0;
        if (s < NSLICE) {
            int cb[2], eb[2];
            #pragma unroll
            for (int h = 0; h < 2; ++h) {
                int k = s * 8 + h * 4, c = 0, base = 0;
                for (; c < 32; ++c) { int rl = ((c >> 2) + 1) << 2; if (k < base + rl) break; base += rl; }
                cb[h] = c * 4; eb[h] = (k - base) * 4;
            }
            v = ((u32)cb[0] << 24) | ((u32)eb[0] << 16) | ((u32)cb[1] << 8) | (u32)eb[1];
        }
        ct[s] = v;
    }
}

// ---------------------------------------------------------------------------
// Main. R17 = R16 verbatim (best: 45.5 us kernel) + fast polynomial atan2
// in the epilogue (branch-free, ~17 VALU vs ~50+ for libm atan2f; poly err
// ~2e-7 rad, negligible vs the 0.0156 output-quantization floor).
// ---------------------------------------------------------------------------
#define TPB   256
#define TSTR  68    // trig row stride (dwords) = 272 B, multiple of 16

__device__ __forceinline__ f16x8 pack8(u32 a, u32 b, u32 c, u32 d) {
    u32x4 t = {a, b, c, d};
    return __builtin_bit_cast(f16x8, t);
}
__device__ __forceinline__ u32 pkrtz_u(float a, float b) {
    return __builtin_bit_cast(u32, __builtin_amdgcn_cvt_pkrtz(a, b));
}

// Branch-free atan2 (~1e-6 rad): octant fold, v_rcp, 6-term odd minimax,
// quadrant restore via selects + copysign. Guard avoids 0/0 -> NaN.
__device__ __forceinline__ float fast_atan2(float y, float x) {
    const float ax = __builtin_fabsf(x), ay = __builtin_fabsf(y);
    const float mx = fmaxf(ax, ay), mn = fminf(ax, ay);
    const float t  = mn * __builtin_amdgcn_rcpf(fmaxf(mx, 1e-37f));
    const float s  = t * t;
    float p = fmaf(s, -0.0117212f, 0.05265332f);
    p = fmaf(s, p, -0.11643287f);
    p = fmaf(s, p,  0.19354346f);
    p = fmaf(s, p, -0.33262347f);
    p = fmaf(s, p,  0.99997726f);
    float a = t * p;                                   // atan(mn/mx) in [0, pi/4+]
    a = (ay > ax) ? (1.5707963268f - a) : a;           // fold: angle from +x axis
    a = (x < 0.0f) ? (3.1415926536f - a) : a;          // left half-plane
    return __builtin_copysignf(a, y);                  // lower half-plane
}

__global__ __launch_bounds__(TPB, 4) void mfma_bilinear(
    const float* __restrict__ x,
    const _Float16* __restrict__ bfr,
    const u32* __restrict__ ct,
    const float* __restrict__ bias,
    float* __restrict__ out)
{
    __shared__ float trig[64 * TSTR];   // 17,408 B

    const int lane = threadIdx.x & 63;
    const int wv   = threadIdx.x >> 6;       // wave id 0..3
    const int lg   = lane >> 4;              // k-subgroup 0..3
    const int lidm = lane & 15;              // A-row / B-col within fragment
    const int P0   = blockIdx.x * 64;
    const int b    = P0 >> 13;
    const int d    = (P0 >> 12) & 1;
    const int hw0  = P0 & 4095;              // 64-aligned, block stays in (b,d)
    const int obase = b * B_STR + d * HW_ + hw0;   // + px + (c|o)*CH_STR

    const int px = wv * 16 + lidm;           // block-local pixel (my A-row)
    float* tp = trig + px * TSTR;
    const char* tb = (const char*)tp;        // byte base of my trig row

    // ---- trig prologue: 4 lanes (lg=0..3) cover the 32 channels of px ----
    #pragma unroll
    for (int m = 0; m < 8; ++m) {
        int c = lg * 8 + m;
        float xv = x[obase + px + c * CH_STR];
        float s, co; __sincosf(xv, &s, &co);
        tp[c]      = co;
        tp[32 + c] = s;
    }
    // same-wave DS ordering makes the reads below safe without a barrier.

    f32x4 acc_r[2] = {{0.f,0.f,0.f,0.f}, {0.f,0.f,0.f,0.f}};
    f32x4 acc_i[2] = {{0.f,0.f,0.f,0.f}, {0.f,0.f,0.f,0.f}};

    // Streaming pointers: uniform base + (lane/lg) voffset + imm offsets.
    const char* ubp = (const char*)bfr;      // step-ks B block at ubp (+= 4096)
    const char* uct = (const char*)ct;       // word(ks) at uct (+= 16)
    const int lo16 = lane * 16;
    const int lg4  = lg * 4;

#define LDB(OFF)      (*(const f16x8*)(ubp + lo16 + (OFF)))
#define LDCT(OFF)     (*(const u32*)(uct + lg4 + (OFF)))
#define LOAD_TRIG(ST, CC0, SC0, CE0, SE0, CC1, SC1, CE1, SE1) do { \
    const u32 st_ = (ST); \
    const int cB0 = (int)(st_ >> 24); \
    const int eB0 = (int)((st_ >> 16) & 0xffu); \
    const int cB1 = (int)((st_ >> 8) & 0xffu); \
    const int eB1 = (int)(st_ & 0xffu); \
    CC0 = *(const float*)(tb + cB0); \
    SC0 = *(const float*)(tb + 128 + cB0); \
    CE0 = *(const f32x4*)(tb + eB0); \
    SE0 = *(const f32x4*)(tb + 128 + eB0); \
    CC1 = *(const float*)(tb + cB1); \
    SC1 = *(const float*)(tb + 128 + cB1); \
    CE1 = *(const f32x4*)(tb + eB1); \
    SE1 = *(const f32x4*)(tb + 128 + eB1); \
} while (0)

// One k-step: u-gen (2 segments) + fp16 RTZ 2-split + 12 MFMA.
#define COMPUTE_STEP(CC0, SC0, CE0, SE0, CC1, SC1, CE1, SE1, BH0, BH1, BL0, BL1) do { \
    const float cs0c = (CC0) * USCALE, cs0s = (SC0) * USCALE; \
    const float cs1c = (CC1) * USCALE, cs1s = (SC1) * USCALE; \
    u32 hr[4], hi[4], lr[4], li[4]; \
    _Pragma("unroll") \
    for (int p = 0; p < 4; ++p) { \
        const float ccs = (p < 2) ? cs0c : cs1c; \
        const float scs = (p < 2) ? cs0s : cs1s; \
        const int i0 = (p & 1) * 2; \
        const float cea = (p < 2) ? (CE0)[i0]     : (CE1)[i0]; \
        const float sea = (p < 2) ? (SE0)[i0]     : (SE1)[i0]; \
        const float ceb = (p < 2) ? (CE0)[i0 + 1] : (CE1)[i0 + 1]; \
        const float seb = (p < 2) ? (SE0)[i0 + 1] : (SE1)[i0 + 1]; \
        const float ur0 = fmaf(ccs, cea, -(scs * sea)); \
        const float ui0 = fmaf(ccs, sea,   scs * cea); \
        const float ur1 = fmaf(ccs, ceb, -(scs * seb)); \
        const float ui1 = fmaf(ccs, seb,   scs * ceb); \
        hr[p] = pkrtz_u(ur0, ur1); \
        hi[p] = pkrtz_u(ui0, ui1); \
        const f16x2 h2r = __builtin_bit_cast(f16x2, hr[p]); \
        const f16x2 h2i = __builtin_bit_cast(f16x2, hi[p]); \
        lr[p] = pkrtz_u(ur0 - (float)h2r[0], ur1 - (float)h2r[1]); \
        li[p] = pkrtz_u(ui0 - (float)h2i[0], ui1 - (float)h2i[1]); \
    } \
    const f16x8 ahr = pack8(hr[0], hr[1], hr[2], hr[3]); \
    const f16x8 ahi = pack8(hi[0], hi[1], hi[2], hi[3]); \
    const f16x8 alr = pack8(lr[0], lr[1], lr[2], lr[3]); \
    const f16x8 ali = pack8(li[0], li[1], li[2], li[3]); \
    acc_r[0] = __builtin_amdgcn_mfma_f32_16x16x32_f16(ahr, BH0, acc_r[0], 0, 0, 0); \
    acc_i[0] = __builtin_amdgcn_mfma_f32_16x16x32_f16(ahi, BH0, acc_i[0], 0, 0, 0); \
    acc_r[1] = __builtin_amdgcn_mfma_f32_16x16x32_f16(ahr, BH1, acc_r[1], 0, 0, 0); \
    acc_i[1] = __builtin_amdgcn_mfma_f32_16x16x32_f16(ahi, BH1, acc_i[1], 0, 0, 0); \
    acc_r[0] = __builtin_amdgcn_mfma_f32_16x16x32_f16(ahr, BL0, acc_r[0], 0, 0, 0); \
    acc_i[0] = __builtin_amdgcn_mfma_f32_16x16x32_f16(ahi, BL0, acc_i[0], 0, 0, 0); \
    acc_r[1] = __builtin_amdgcn_mfma_f32_16x16x32_f16(ahr, BL1, acc_r[1], 0, 0, 0); \
    acc_i[1] = __builtin_amdgcn_mfma_f32_16x16x32_f16(ahi, BL1, acc_i[1], 0, 0, 0); \
    acc_r[0] = __builtin_amdgcn_mfma_f32_16x16x32_f16(alr, BH0, acc_r[0], 0, 0, 0); \
    acc_i[0] = __builtin_amdgcn_mfma_f32_16x16x32_f16(ali, BH0, acc_i[0], 0, 0, 0); \
    acc_r[1] = __builtin_amdgcn_mfma_f32_16x16x32_f16(alr, BH1, acc_r[1], 0, 0, 0); \
    acc_i[1] = __builtin_amdgcn_mfma_f32_16x16x32_f16(ali, BH1, acc_i[1], 0, 0, 0); \
} while (0)

    // ---- pipeline prologue: step-0 state + descriptor for step 1 ----
    f16x8 bh0 = LDB(0), bh1 = LDB(1024), bl0 = LDB(2048), bl1 = LDB(3072);
    float cc0, sc0, cc1, sc1; f32x4 ce0, se0, ce1, se1;
    LOAD_TRIG(LDCT(0), cc0, sc0, ce0, se0, cc1, sc1, ce1, se1);
    u32 stN = LDCT(16);
    ubp += 4096;                         // -> step 1 block

    #pragma unroll 4
    for (int ks = 0; ks < NKSTEP - 1; ++ks) {
        // prefetch step ks+1 (B block at ubp; trig via stN; word for ks+2)
        f16x8 nbh0 = LDB(0), nbh1 = LDB(1024), nbl0 = LDB(2048), nbl1 = LDB(3072);
        float ncc0, nsc0, ncc1, nsc1; f32x4 nce0, nse0, nce1, nse1;
        LOAD_TRIG(stN, ncc0, nsc0, nce0, nse0, ncc1, nsc1, nce1, nse1);
        u32 stN2 = LDCT(32);             // word(ks+2); padded table keeps in-bounds

        COMPUTE_STEP(cc0, sc0, ce0, se0, cc1, sc1, ce1, se1, bh0, bh1, bl0, bl1);

        bh0 = nbh0; bh1 = nbh1; bl0 = nbl0; bl1 = nbl1;
        cc0 = ncc0; sc0 = nsc0; cc1 = ncc1; sc1 = nsc1;
        ce0 = nce0; se0 = nse0; ce1 = nce1; se1 = nse1;
        stN = stN2;
        ubp += 4096; uct += 16;
    }
    // peeled final step (no prefetch, no clamps anywhere)
    COMPUTE_STEP(cc0, sc0, ce0, se0, cc1, sc1, ce1, se1, bh0, bh1, bl0, bl1);

    // ---- epilogue: C/D (m89): col o = oh*16 + (lane&15), row px = 4*lg + q ----
    #pragma unroll
    for (int oh = 0; oh < 2; ++oh) {
        const int o = oh * 16 + lidm;
        const float bo = bias[o];
        #pragma unroll
        for (int q = 0; q < 4; ++q) {
            const int pxr = wv * 16 + lg * 4 + q;
            out[obase + pxr + o * CH_STR] = fast_atan2(acc_i[oh][q], acc_r[oh][q]) + bo;
        }
    }
#undef LDB
#undef LDCT
#undef LOAD_TRIG
#undef COMPUTE_STEP
}

// ---------------------------------------------------------------------------
extern "C" void kernel_launch(void* const* d_in, const int* in_sizes, int n_in,
                              void* d_out, int out_size, void* d_ws, size_t ws_size,
                              hipStream_t stream) {
    const float* x    = (const float*)d_in[0];
    const float* w    = (const float*)d_in[1];
    const float* bias = (const float*)d_in[2];
    float* out        = (float*)d_out;
    _Float16* bfr = (_Float16*)d_ws;                  // 73,728 B
    u32*      ct  = (u32*)((char*)d_ws + 73728);      // 304 B

    {
        int n = NBEL + NCT;
        prep<<<(n + 255) / 256, 256, 0, stream>>>(w, bfr, ct);
    }
    {
        int grid = NPIX / 64;   // 2048 blocks x 4 waves
        mfma_bilinear<<<grid, TPB, 0, stream>>>(x, bfr, ct, bias, out);
    }
}